// Round 19
// baseline (319.843 us; speedup 1.0000x reference)
//
#include <hip/hip_runtime.h>
#include <hip/hip_fp16.h>

#define HH 96
#define WW 96
#define CC 21
#define NN (HH*WW)          // 9216
#define NBLK (NN/256)       // 36
#define STRIDE 24           // 21 classes + r,g,b packed in padding
#define ROWF (WW*STRIDE)    // 2304
#define NRUN (NN/8)         // 1152
#define NTILE 576
// QT2 layout: [jrun][24 classes][8 px] f16, 384 B per run-block.

typedef _Float16 f16x8 __attribute__((ext_vector_type(8)));
typedef float f32x4 __attribute__((ext_vector_type(4)));

union H8 { f16x8 v; __half2 h2[4]; };

// ---------------------------------------------------------------------------
// ws layout (floats): U Qa Qb [NN*24 each], partial[64], pad[64],
// QT2a QT2b [NRUN*192 f16]
// ---------------------------------------------------------------------------

__global__ __launch_bounds__(256) void k_setup(
    const float* __restrict__ logits, const int* __restrict__ labels,
    const float* __restrict__ image, float* __restrict__ U,
    float* __restrict__ Q0, _Float16* __restrict__ QTa,
    _Float16* __restrict__ QTb, float* __restrict__ partial) {
  const int t = threadIdx.x;
  const int i = blockIdx.x * 256 + t;
  const int qoff = (i >> 3) * 192 + (i & 7);

  float d[CC];
  float mx = -1e30f;
#pragma unroll
  for (int c = 0; c < CC; ++c) {
    d[c] = logits[c * NN + i];
    mx = fmaxf(mx, d[c]);
  }
  float s = 0.f;
#pragma unroll
  for (int c = 0; c < CC; ++c) { d[c] -= mx; s += __expf(d[c]); }
  const float lse = logf(s);
  const float inv = 1.f / s;
  const int lab = labels[i];
  float myU = 0.f;
#pragma unroll
  for (int c = 0; c < CC; ++c) {
    const float Uc = lse - d[c];
    const float q = __expf(d[c]) * inv;
    U[i * STRIDE + c] = Uc;
    Q0[i * STRIDE + c] = q;
    QTa[qoff + c * 8] = (_Float16)q;
    myU = (c == lab) ? Uc : myU;
  }
  const float rr = image[i] * (1.f / 255.f);
  const float rg = image[NN + i] * (1.f / 255.f);
  const float rb = image[2 * NN + i] * (1.f / 255.f);
  U[i * STRIDE + 21] = 0.f;
  U[i * STRIDE + 22] = 0.f;
  U[i * STRIDE + 23] = 0.f;
  Q0[i * STRIDE + 21] = rr;
  Q0[i * STRIDE + 22] = rg;
  Q0[i * STRIDE + 23] = rb;
  QTa[qoff + 21 * 8] = (_Float16)rr;
  QTa[qoff + 22 * 8] = (_Float16)rg;
  QTa[qoff + 23 * 8] = (_Float16)rb;
  QTb[qoff + 21 * 8] = (_Float16)rr;
  QTb[qoff + 22 * 8] = (_Float16)rg;
  QTb[qoff + 23 * 8] = (_Float16)rb;

  __shared__ float red[256];
  red[t] = myU;
  __syncthreads();
  for (int off = 128; off > 0; off >>= 1) {
    if (t < off) red[t] += red[t + off];
    __syncthreads();
  }
  if (t == 0) partial[blockIdx.x] = red[0];
}

// ---------------------------------------------------------------------------
// Fully-fused iteration kernel: per-block gauss-y (4 rows -> LDS) +
// MFMA bilateral + gauss-x-at-outputs + mean-field update (+ final output).
// block = 512 thr = 8 waves = one 4x4 pixel tile; 576 blocks; 6 dispatches
// total for the whole problem (setup + 5x this).
// ---------------------------------------------------------------------------
__global__ __launch_bounds__(512) void k_bilat(
    const float* __restrict__ U, const float* __restrict__ Qin,
    const _Float16* __restrict__ QT, float* __restrict__ Qout,
    _Float16* __restrict__ QTout, const float* __restrict__ partial,
    float* __restrict__ out, int last) {
  __shared__ float sGy[4 * ROWF];       // 36864 B: Gy rows ty0..ty0+3
  __shared__ float psum[8][16][24];     // 12288 B
  __shared__ __half sytab[64];
  __shared__ __half2 sxtab[64];
  __shared__ float sgt[96];
  __shared__ float sces;

  const int tid = threadIdx.x;
  const int w = tid >> 6;
  const int l = tid & 63;
  const int g = l >> 4;
  const int q = l & 15;

  const int tile = blockIdx.x;
  const int ty0 = (tile / 24) * 4;
  const int tx0 = (tile - (tile / 24) * 24) * 4;

  // tables
  if (tid < 96) {
    const float dv = (float)tid * (1.f / 64.f);
    sgt[tid] = __expf(-0.5f * dv * dv);
  }
  if (tid >= 128 && tid < 192) {
    const int k = tid - 128;
    const float dv = (float)(k - 32);
    sytab[k] = __float2half(__expf(dv * dv * (-1.f / 18.f)));
    const float dv1 = dv + 1.f;
    sxtab[k] = __floats2half2_rn(__expf(dv * dv * (-1.f / 18.f)),
                                 __expf(dv1 * dv1 * (-1.f / 18.f)));
  }
  if (last && tid < 64) {
    float v = (tid < NBLK) ? partial[tid] : 0.f;
#pragma unroll
    for (int off = 32; off >= 1; off >>= 1) v += __shfl_xor(v, off, 64);
    if (tid == 0) sces = v * (1.f / (float)NN);
  }
  __syncthreads();   // sgt ready for phase A

  // ---- phase A: gauss-y for rows ty0..ty0+3 into LDS ----
  // thread handles (x,c) columns p = tid, tid+512, ... ; coalesced f32 reads.
#pragma unroll
  for (int k = 0; k < 5; ++k) {
    const int p = tid + (k << 9);
    if (p < ROWF) {
      const float* col = Qin + p;
      float a0 = 0.f, a1 = 0.f, a2 = 0.f, a3 = 0.f;
#pragma unroll 6
      for (int yp = 0; yp < HH; ++yp) {
        const float v = col[yp * ROWF];
        const int d = ty0 - yp;
        a0 = fmaf(sgt[abs(d)], v, a0);
        a1 = fmaf(sgt[abs(d + 1)], v, a1);
        a2 = fmaf(sgt[abs(d + 2)], v, a2);
        a3 = fmaf(sgt[abs(d + 3)], v, a3);
      }
      sGy[0 * ROWF + p] = a0;
      sGy[1 * ROWF + p] = a1;
      sGy[2 * ROWF + p] = a2;
      sGy[3 * ROWF + p] = a3;
    }
  }

  // ---- MFMA bilateral main loop (reads QT only) ----
  const int pr = q >> 2, pc = q & 3;
  const int yi = ty0 + pr, xi = tx0 + pc;
  const int ipix = yi * WW + xi;

  const float4 rown = *(const float4*)(Qin + ipix * STRIDE + 20);
  const __half2 ri_r = __float2half2_rn(rown.y);
  const __half2 ri_g = __float2half2_rn(rown.z);
  const __half2 ri_b = __float2half2_rn(rown.w);
  const __half2 mhalf = __floats2half2_rn(-0.5f, -0.5f);
  const __half hzero = __float2half(0.f);

  const int xs = tx0 - 16;
  const int xbase0 = (xs > 0 ? xs : 0) & ~7;
  const int rid0 = (w < 4) ? w * 23 : 92 + (w - 4) * 22;
  const int nrun = (w < 4) ? 23 : 22;
  const int row2 = (16 + q > 23) ? 23 : 16 + q;

  f32x4 acc0 = {0.f, 0.f, 0.f, 0.f};
  f32x4 acc1 = {0.f, 0.f, 0.f, 0.f};

#pragma unroll
  for (int ck = 0; ck < 6; ++ck) {
    const int r = ck * 4 + g;
    const int rid = rid0 + r;
    const int wr = rid / 5;
    const int cs = rid - wr * 5;
    const int yj = ty0 - 16 + wr;
    const int xb = xbase0 + cs * 8;
    const bool ok = (r < nrun) & (yj >= 0) & (yj < HH) & (xb <= WW - 8);
    const int yc = min(max(yj, 0), HH - 1);
    const int xc = min(xb, WW - 8);
    const _Float16* base = QT + (yc * 12 + (xc >> 3)) * 192;

    H8 b1, b2, rj, gj, bj;
    b1.v = *(const f16x8*)(base + q * 8);
    b2.v = *(const f16x8*)(base + row2 * 8);
    rj.v = *(const f16x8*)(base + 21 * 8);
    gj.v = *(const f16x8*)(base + 22 * 8);
    bj.v = *(const f16x8*)(base + 23 * 8);

    const int dy = yj - yi;
    const int iy = min(max(dy + 32, 0), 63);
    const __half syv = ok ? sytab[iy] : hzero;
    const __half2 sy2 = __half2half2(syv);
    const int dx0 = xb - xi;
    const int ix0 = min(max(dx0 + 32, 0), 57);

    H8 af;
#pragma unroll
    for (int e2 = 0; e2 < 4; ++e2) {
      const __half2 sx2 = sxtab[ix0 + 2 * e2];
      const __half2 dr = __hsub2(rj.h2[e2], ri_r);
      const __half2 dg = __hsub2(gj.h2[e2], ri_g);
      const __half2 db = __hsub2(bj.h2[e2], ri_b);
      __half2 d2c = __hmul2(dr, dr);
      d2c = __hfma2(dg, dg, d2c);
      d2c = __hfma2(db, db, d2c);
      const __half2 ec = h2exp(__hmul2(d2c, mhalf));
      af.h2[e2] = __hmul2(__hmul2(sy2, sx2), ec);
    }
    acc0 = __builtin_amdgcn_mfma_f32_16x16x32_f16(af.v, b1.v, acc0, 0, 0, 0);
    acc1 = __builtin_amdgcn_mfma_f32_16x16x32_f16(af.v, b2.v, acc1, 0, 0, 0);
  }

#pragma unroll
  for (int reg = 0; reg < 4; ++reg) {
    psum[w][g * 4 + reg][q] = acc0[reg];
    if (q < 8) psum[w][g * 4 + reg][16 + q] = acc1[reg];
  }
  __syncthreads();   // psum + sGy both complete

  // ---- epilogue: cross-wave sum + gauss-x from LDS + mean-field update ----
  const int half_ = l >> 5;
  const int cl = l & 31;
  const bool act = cl < CC;
  const int pix = w * 2 + half_;
  const int py = ty0 + (pix >> 2), px = tx0 + (pix & 3);
  const int ip = py * WW + px;
  float Qic = 0.f;
  if (cl < STRIDE) Qic = Qin[ip * STRIDE + cl];
  float tcv = 0.f, Uc = 0.f, Gc = 0.f;
  if (act) {
    tcv = psum[0][pix][cl] + psum[1][pix][cl] + psum[2][pix][cl] +
          psum[3][pix][cl] + psum[4][pix][cl] + psum[5][pix][cl] +
          psum[6][pix][cl] + psum[7][pix][cl];
    Uc = U[ip * STRIDE + cl];
    // gauss-x over the LDS-resident Gy row (pix>>2), 4 chains
    const float* grow = sGy + (pix >> 2) * ROWF + cl;
    float g0 = 0.f, g1 = 0.f, g2 = 0.f, g3 = 0.f;
#pragma unroll 6
    for (int xp = 0; xp < WW; xp += 4) {
      g0 = fmaf(sgt[abs(px - xp)], grow[xp * STRIDE], g0);
      g1 = fmaf(sgt[abs(px - xp - 1)], grow[(xp + 1) * STRIDE], g1);
      g2 = fmaf(sgt[abs(px - xp - 2)], grow[(xp + 2) * STRIDE], g2);
      g3 = fmaf(sgt[abs(px - xp - 3)], grow[(xp + 3) * STRIDE], g3);
    }
    Gc = (g0 + g1) + (g2 + g3);
  }
  const float contrib = act ? (tcv + Gc - 2.f * Qic) : 0.f;  // self removed
  float tot = contrib;
#pragma unroll
  for (int off = 16; off >= 1; off >>= 1) tot += __shfl_xor(tot, off, 32);
  const float lc = act ? (-Uc - 10.f * (tot - contrib)) : -1e30f;
  float mxl = lc;
#pragma unroll
  for (int off = 16; off >= 1; off >>= 1)
    mxl = fmaxf(mxl, __shfl_xor(mxl, off, 32));
  const float e = act ? __expf(lc - mxl) : 0.f;
  float se = e;
#pragma unroll
  for (int off = 16; off >= 1; off >>= 1) se += __shfl_xor(se, off, 32);
  const float qnew = e / se;
  if (last) {
    if (act) out[cl * NN + ip] = sces + qnew;    // final CHW output
  } else {
    if (cl < STRIDE) Qout[ip * STRIDE + cl] = act ? qnew : Qic;
    if (act) QTout[(ip >> 3) * 192 + cl * 8 + (ip & 7)] = (_Float16)qnew;
  }
}

extern "C" void kernel_launch(void* const* d_in, const int* in_sizes, int n_in,
                              void* d_out, int out_size, void* d_ws,
                              size_t ws_size, hipStream_t stream) {
  const float* logits = (const float*)d_in[0];
  const int* labels = (const int*)d_in[1];
  const float* image = (const float*)d_in[2];
  float* ws = (float*)d_ws;

  float* U = ws;
  float* Qa = U + NN * STRIDE;
  float* Qb = Qa + NN * STRIDE;
  float* partial = Qb + NN * STRIDE;
  float* cepad = partial + 64;
  _Float16* QTa = (_Float16*)(cepad + 64);
  _Float16* QTb = QTa + NRUN * 192;

  k_setup<<<NBLK, 256, 0, stream>>>(logits, labels, image, U, Qa, QTa, QTb,
                                    partial);

  const float* qi = Qa;
  float* qo = Qb;
  const _Float16* qti = QTa;
  _Float16* qto = QTb;
  for (int it = 0; it < 5; ++it) {
    k_bilat<<<NTILE, 512, 0, stream>>>(U, qi, qti, qo, qto, partial,
                                       (float*)d_out, it == 4);
    qi = qo;
    qo = (qo == Qb) ? Qa : Qb;
    const _Float16* tmp = qti;
    qti = qto;
    qto = (_Float16*)tmp;
  }
}

// Round 20
// 178.356 us; speedup vs baseline: 1.7933x; 1.7933x over previous
//
#include <hip/hip_runtime.h>
#include <hip/hip_fp16.h>

#define HH 96
#define WW 96
#define CC 21
#define NN (HH*WW)          // 9216
#define NBLK (NN/256)       // 36
#define STRIDE 24           // 21 classes + r,g,b packed in padding
#define ROWF (WW*STRIDE)    // 2304
#define NRUN (NN/8)         // 1152
#define NTILE 576
// QT2 layout: [jrun][24 classes][8 px] f16, 384 B per run-block.

typedef _Float16 f16x8 __attribute__((ext_vector_type(8)));
typedef float f32x4 __attribute__((ext_vector_type(4)));

union H8 { f16x8 v; __half2 h2[4]; };

// ---------------------------------------------------------------------------
// ws layout (floats): U Qa Qb G [NN*24 each], partial[64], pad[64],
// QT2a QT2b [NRUN*192 f16]
// ---------------------------------------------------------------------------

__global__ __launch_bounds__(256) void k_setup(
    const float* __restrict__ logits, const int* __restrict__ labels,
    const float* __restrict__ image, float* __restrict__ U,
    float* __restrict__ Q0, _Float16* __restrict__ QTa,
    _Float16* __restrict__ QTb, float* __restrict__ partial) {
  const int t = threadIdx.x;
  const int i = blockIdx.x * 256 + t;
  const int qoff = (i >> 3) * 192 + (i & 7);

  float d[CC];
  float mx = -1e30f;
#pragma unroll
  for (int c = 0; c < CC; ++c) {
    d[c] = logits[c * NN + i];
    mx = fmaxf(mx, d[c]);
  }
  float s = 0.f;
#pragma unroll
  for (int c = 0; c < CC; ++c) { d[c] -= mx; s += __expf(d[c]); }
  const float lse = logf(s);
  const float inv = 1.f / s;
  const int lab = labels[i];
  float myU = 0.f;
#pragma unroll
  for (int c = 0; c < CC; ++c) {
    const float Uc = lse - d[c];
    const float q = __expf(d[c]) * inv;
    U[i * STRIDE + c] = Uc;
    Q0[i * STRIDE + c] = q;
    QTa[qoff + c * 8] = (_Float16)q;
    myU = (c == lab) ? Uc : myU;
  }
  const float rr = image[i] * (1.f / 255.f);
  const float rg = image[NN + i] * (1.f / 255.f);
  const float rb = image[2 * NN + i] * (1.f / 255.f);
  U[i * STRIDE + 21] = 0.f;
  U[i * STRIDE + 22] = 0.f;
  U[i * STRIDE + 23] = 0.f;
  Q0[i * STRIDE + 21] = rr;
  Q0[i * STRIDE + 22] = rg;
  Q0[i * STRIDE + 23] = rb;
  QTa[qoff + 21 * 8] = (_Float16)rr;
  QTa[qoff + 22 * 8] = (_Float16)rg;
  QTa[qoff + 23 * 8] = (_Float16)rb;
  QTb[qoff + 21 * 8] = (_Float16)rr;
  QTb[qoff + 22 * 8] = (_Float16)rg;
  QTb[qoff + 23 * 8] = (_Float16)rb;

  __shared__ float red[256];
  red[t] = myU;
  __syncthreads();
  for (int off = 128; off > 0; off >>= 1) {
    if (t < off) red[t] += red[t + off];
    __syncthreads();
  }
  if (t == 0) partial[blockIdx.x] = red[0];
}

// ---------------------------------------------------------------------------
// Fused separable gaussian (sigma 64), ZERO redundancy: block = one image
// row y. Phase 1: Gy row y (96-tap column filter, coalesced) -> LDS.
// Phase 2: x-pass from LDS (broadcast reads, conflict-free) -> G row y.
// 96 blocks x 1024 threads. Replaces two kernels + global intermediate.
// ---------------------------------------------------------------------------
__global__ __launch_bounds__(1024) void k_gauss(
    const float* __restrict__ Qin, float* __restrict__ G) {
  __shared__ float sGy[ROWF];   // 9216 B
  __shared__ float g[96];

  const int tid = threadIdx.x;
  const int y = blockIdx.x;
  if (tid < 96) {
    const float dv = (float)tid * (1.f / 64.f);
    g[tid] = __expf(-0.5f * dv * dv);
  }
  __syncthreads();

#pragma unroll
  for (int k = 0; k < 3; ++k) {
    const int p = tid + (k << 10);
    if (p < ROWF) {
      const float* col = Qin + p;
      float a0 = 0.f, a1 = 0.f, a2 = 0.f, a3 = 0.f;
#pragma unroll 6
      for (int yp = 0; yp < HH; yp += 4) {
        a0 = fmaf(g[abs(y - yp)], col[yp * ROWF], a0);
        a1 = fmaf(g[abs(y - yp - 1)], col[(yp + 1) * ROWF], a1);
        a2 = fmaf(g[abs(y - yp - 2)], col[(yp + 2) * ROWF], a2);
        a3 = fmaf(g[abs(y - yp - 3)], col[(yp + 3) * ROWF], a3);
      }
      sGy[p] = (a0 + a1) + (a2 + a3);
    }
  }
  __syncthreads();

#pragma unroll
  for (int k = 0; k < 3; ++k) {
    const int p = tid + (k << 10);
    if (p < ROWF) {
      const int x = p / STRIDE;
      const int c = p - x * STRIDE;
      const float* base = sGy + c;
      float a0 = 0.f, a1 = 0.f, a2 = 0.f, a3 = 0.f;
#pragma unroll 6
      for (int xp = 0; xp < WW; xp += 4) {
        a0 = fmaf(g[abs(x - xp)], base[xp * STRIDE], a0);
        a1 = fmaf(g[abs(x - xp - 1)], base[(xp + 1) * STRIDE], a1);
        a2 = fmaf(g[abs(x - xp - 2)], base[(xp + 2) * STRIDE], a2);
        a3 = fmaf(g[abs(x - xp - 3)], base[(xp + 3) * STRIDE], a3);
      }
      G[y * ROWF + p] = (a0 + a1) + (a2 + a3);
    }
  }
}

// ---------------------------------------------------------------------------
// MFMA bilateral + mean-field update (+ final output). G precomputed.
// block = 256 thr = 4 waves = one 4x4 pixel tile; 576 blocks. 45 runs/wave
// (exactly even), 12 chunks of 4 runs -> 24 MFMA/wave. Finer blocks than
// the 8-wave version: cheaper barriers, better CU packing granularity.
// ---------------------------------------------------------------------------
__global__ __launch_bounds__(256) void k_bilat(
    const float* __restrict__ U, const float* __restrict__ Qin,
    const float* __restrict__ G, const _Float16* __restrict__ QT,
    float* __restrict__ Qout, _Float16* __restrict__ QTout,
    const float* __restrict__ partial, float* __restrict__ out, int last) {
  __shared__ __half sytab[64];
  __shared__ __half2 sxtab[64];
  __shared__ float psum[4][16][24];   // 6144 B
  __shared__ float sces;

  const int tid = threadIdx.x;
  const int w = tid >> 6;        // wave 0..3
  const int l = tid & 63;
  const int g = l >> 4;
  const int q = l & 15;

  if (tid < 64) {
    const float dv = (float)(tid - 32);
    sytab[tid] = __float2half(__expf(dv * dv * (-1.f / 18.f)));
    const float dv1 = dv + 1.f;
    sxtab[tid] = __floats2half2_rn(__expf(dv * dv * (-1.f / 18.f)),
                                   __expf(dv1 * dv1 * (-1.f / 18.f)));
    if (last) {
      float v = (tid < NBLK) ? partial[tid] : 0.f;
#pragma unroll
      for (int off = 32; off >= 1; off >>= 1) v += __shfl_xor(v, off, 64);
      if (tid == 0) sces = v * (1.f / (float)NN);
    }
  }
  __syncthreads();

  const int tile = blockIdx.x;
  const int ty0 = (tile / 24) * 4;
  const int tx0 = (tile - (tile / 24) * 24) * 4;

  const int pr = q >> 2, pc = q & 3;
  const int yi = ty0 + pr, xi = tx0 + pc;
  const int ipix = yi * WW + xi;

  const float4 rown = *(const float4*)(Qin + ipix * STRIDE + 20);
  const __half2 ri_r = __float2half2_rn(rown.y);
  const __half2 ri_g = __float2half2_rn(rown.z);
  const __half2 ri_b = __float2half2_rn(rown.w);
  const __half2 mhalf = __floats2half2_rn(-0.5f, -0.5f);
  const __half hzero = __float2half(0.f);

  const int xs = tx0 - 16;
  const int xbase0 = (xs > 0 ? xs : 0) & ~7;
  const int rid0 = w * 45;           // 180 runs / 4 waves, exactly even
  const int row2 = (16 + q > 23) ? 23 : 16 + q;

  f32x4 acc0 = {0.f, 0.f, 0.f, 0.f};
  f32x4 acc1 = {0.f, 0.f, 0.f, 0.f};

#pragma unroll
  for (int ck = 0; ck < 12; ++ck) {
    const int r = ck * 4 + g;        // 0..47; r<45 valid
    const int rid = rid0 + r;
    const int wr = rid / 5;
    const int cs = rid - wr * 5;
    const int yj = ty0 - 16 + wr;
    const int xb = xbase0 + cs * 8;
    const bool ok = (r < 45) & (yj >= 0) & (yj < HH) & (xb <= WW - 8);
    const int yc = min(max(yj, 0), HH - 1);
    const int xc = min(xb, WW - 8);
    const _Float16* base = QT + (yc * 12 + (xc >> 3)) * 192;

    H8 b1, b2, rj, gj, bj;
    b1.v = *(const f16x8*)(base + q * 8);
    b2.v = *(const f16x8*)(base + row2 * 8);
    rj.v = *(const f16x8*)(base + 21 * 8);
    gj.v = *(const f16x8*)(base + 22 * 8);
    bj.v = *(const f16x8*)(base + 23 * 8);

    const int dy = yj - yi;
    const int iy = min(max(dy + 32, 0), 63);
    const __half syv = ok ? sytab[iy] : hzero;
    const __half2 sy2 = __half2half2(syv);
    const int dx0 = xb - xi;
    const int ix0 = min(max(dx0 + 32, 0), 57);

    H8 af;
#pragma unroll
    for (int e2 = 0; e2 < 4; ++e2) {
      const __half2 sx2 = sxtab[ix0 + 2 * e2];
      const __half2 dr = __hsub2(rj.h2[e2], ri_r);
      const __half2 dg = __hsub2(gj.h2[e2], ri_g);
      const __half2 db = __hsub2(bj.h2[e2], ri_b);
      __half2 d2c = __hmul2(dr, dr);
      d2c = __hfma2(dg, dg, d2c);
      d2c = __hfma2(db, db, d2c);
      const __half2 ec = h2exp(__hmul2(d2c, mhalf));
      af.h2[e2] = __hmul2(__hmul2(sy2, sx2), ec);
    }
    acc0 = __builtin_amdgcn_mfma_f32_16x16x32_f16(af.v, b1.v, acc0, 0, 0, 0);
    acc1 = __builtin_amdgcn_mfma_f32_16x16x32_f16(af.v, b2.v, acc1, 0, 0, 0);
  }

#pragma unroll
  for (int reg = 0; reg < 4; ++reg) {
    psum[w][g * 4 + reg][q] = acc0[reg];
    if (q < 8) psum[w][g * 4 + reg][16 + q] = acc1[reg];
  }
  __syncthreads();

  // mean-field update: wave w owns pixels 4w..4w+3 (2 per 32-half, 2 passes)
  const int half_ = l >> 5;
  const int cl = l & 31;
  const bool act = cl < CC;
#pragma unroll
  for (int p2 = 0; p2 < 2; ++p2) {
    const int pix = (w << 2) + (half_ << 1) + p2;
    const int py = ty0 + (pix >> 2), px = tx0 + (pix & 3);
    const int ip = py * WW + px;
    float Qic = 0.f;
    if (cl < STRIDE) Qic = Qin[ip * STRIDE + cl];
    float tcv = 0.f, Uc = 0.f, Gc = 0.f;
    if (act) {
      tcv = psum[0][pix][cl] + psum[1][pix][cl] + psum[2][pix][cl] +
            psum[3][pix][cl];
      Uc = U[ip * STRIDE + cl];
      Gc = G[ip * STRIDE + cl];
    }
    const float contrib = act ? (tcv + Gc - 2.f * Qic) : 0.f;  // self removed
    float tot = contrib;
#pragma unroll
    for (int off = 16; off >= 1; off >>= 1) tot += __shfl_xor(tot, off, 32);
    const float lc = act ? (-Uc - 10.f * (tot - contrib)) : -1e30f;
    float mxl = lc;
#pragma unroll
    for (int off = 16; off >= 1; off >>= 1)
      mxl = fmaxf(mxl, __shfl_xor(mxl, off, 32));
    const float e = act ? __expf(lc - mxl) : 0.f;
    float se = e;
#pragma unroll
    for (int off = 16; off >= 1; off >>= 1) se += __shfl_xor(se, off, 32);
    const float qnew = e / se;
    if (last) {
      if (act) out[cl * NN + ip] = sces + qnew;    // final CHW output
    } else {
      if (cl < STRIDE) Qout[ip * STRIDE + cl] = act ? qnew : Qic;
      if (act) QTout[(ip >> 3) * 192 + cl * 8 + (ip & 7)] = (_Float16)qnew;
    }
  }
}

extern "C" void kernel_launch(void* const* d_in, const int* in_sizes, int n_in,
                              void* d_out, int out_size, void* d_ws,
                              size_t ws_size, hipStream_t stream) {
  const float* logits = (const float*)d_in[0];
  const int* labels = (const int*)d_in[1];
  const float* image = (const float*)d_in[2];
  float* ws = (float*)d_ws;

  float* U = ws;
  float* Qa = U + NN * STRIDE;
  float* Qb = Qa + NN * STRIDE;
  float* G = Qb + NN * STRIDE;
  float* partial = G + NN * STRIDE;
  float* cepad = partial + 64;
  _Float16* QTa = (_Float16*)(cepad + 64);
  _Float16* QTb = QTa + NRUN * 192;

  k_setup<<<NBLK, 256, 0, stream>>>(logits, labels, image, U, Qa, QTa, QTb,
                                    partial);

  const float* qi = Qa;
  float* qo = Qb;
  const _Float16* qti = QTa;
  _Float16* qto = QTb;
  for (int it = 0; it < 5; ++it) {
    k_gauss<<<HH, 1024, 0, stream>>>(qi, G);
    k_bilat<<<NTILE, 256, 0, stream>>>(U, qi, G, qti, qo, qto, partial,
                                       (float*)d_out, it == 4);
    qi = qo;
    qo = (qo == Qb) ? Qa : Qb;
    const _Float16* tmp = qti;
    qti = qto;
    qto = (_Float16*)tmp;
  }
}

// Round 21
// 136.542 us; speedup vs baseline: 2.3424x; 1.3062x over previous
//
#include <hip/hip_runtime.h>
#include <hip/hip_fp16.h>

#define HH 96
#define WW 96
#define CC 21
#define NN (HH*WW)          // 9216
#define NBLK (NN/256)       // 36
#define STRIDE 24           // 21 classes + r,g,b packed in padding
#define ROWF (WW*STRIDE)    // 2304
#define NRUN (NN/8)         // 1152
#define NTILE 576
// QT2 layout: [jrun][24 classes][8 px] f16, 384 B per run-block.

typedef _Float16 f16x8 __attribute__((ext_vector_type(8)));
typedef float f32x4 __attribute__((ext_vector_type(4)));

union H8 { f16x8 v; __half2 h2[4]; };

// ---------------------------------------------------------------------------
// ws layout (floats): U Qa Qb Gy G [NN*24 each], gtab[96], partial[64],
// pad[64], QT2a QT2b [NRUN*192 f16]
// ---------------------------------------------------------------------------

__global__ __launch_bounds__(256) void k_setup(
    const float* __restrict__ logits, const int* __restrict__ labels,
    const float* __restrict__ image, float* __restrict__ U,
    float* __restrict__ Q0, _Float16* __restrict__ QTa,
    _Float16* __restrict__ QTb, float* __restrict__ gtab,
    float* __restrict__ partial) {
  const int t = threadIdx.x;
  const int i = blockIdx.x * 256 + t;
  const int qoff = (i >> 3) * 192 + (i & 7);

  float d[CC];
  float mx = -1e30f;
#pragma unroll
  for (int c = 0; c < CC; ++c) {
    d[c] = logits[c * NN + i];
    mx = fmaxf(mx, d[c]);
  }
  float s = 0.f;
#pragma unroll
  for (int c = 0; c < CC; ++c) { d[c] -= mx; s += __expf(d[c]); }
  const float lse = logf(s);
  const float inv = 1.f / s;
  const int lab = labels[i];
  float myU = 0.f;
#pragma unroll
  for (int c = 0; c < CC; ++c) {
    const float Uc = lse - d[c];
    const float q = __expf(d[c]) * inv;
    U[i * STRIDE + c] = Uc;
    Q0[i * STRIDE + c] = q;
    QTa[qoff + c * 8] = (_Float16)q;
    myU = (c == lab) ? Uc : myU;
  }
  const float rr = image[i] * (1.f / 255.f);
  const float rg = image[NN + i] * (1.f / 255.f);
  const float rb = image[2 * NN + i] * (1.f / 255.f);
  U[i * STRIDE + 21] = 0.f;
  U[i * STRIDE + 22] = 0.f;
  U[i * STRIDE + 23] = 0.f;
  Q0[i * STRIDE + 21] = rr;
  Q0[i * STRIDE + 22] = rg;
  Q0[i * STRIDE + 23] = rb;
  QTa[qoff + 21 * 8] = (_Float16)rr;
  QTa[qoff + 22 * 8] = (_Float16)rg;
  QTa[qoff + 23 * 8] = (_Float16)rb;
  QTb[qoff + 21 * 8] = (_Float16)rr;
  QTb[qoff + 22 * 8] = (_Float16)rg;
  QTb[qoff + 23 * 8] = (_Float16)rb;

  if (blockIdx.x == 0 && t < 96) {
    const float dv = (float)t * (1.f / 64.f);
    gtab[t] = __expf(-0.5f * dv * dv);
  }

  __shared__ float red[256];
  red[t] = myU;
  __syncthreads();
  for (int off = 128; off > 0; off >>= 1) {
    if (t < off) red[t] += red[t + off];
    __syncthreads();
  }
  if (t == 0) partial[blockIdx.x] = red[0];
}

// separable long-range gaussian (sigma 64), y pass, 864 blocks.
__global__ __launch_bounds__(256) void k_gauss_y(
    const float* __restrict__ Qin, float* __restrict__ Gy,
    const float* __restrict__ gtab) {
  __shared__ float g[96];
  if (threadIdx.x < 96) g[threadIdx.x] = gtab[threadIdx.x];
  __syncthreads();
  const int idx = blockIdx.x * 256 + threadIdx.x;
  const int y = idx / ROWF;
  const int rem = idx - y * ROWF;
  const float* base = Qin + rem;
  float a0 = 0.f, a1 = 0.f, a2 = 0.f, a3 = 0.f;
#pragma unroll 6
  for (int yp = 0; yp < HH; yp += 4) {
    a0 = fmaf(g[abs(y - yp)], base[yp * ROWF], a0);
    a1 = fmaf(g[abs(y - yp - 1)], base[(yp + 1) * ROWF], a1);
    a2 = fmaf(g[abs(y - yp - 2)], base[(yp + 2) * ROWF], a2);
    a3 = fmaf(g[abs(y - yp - 3)], base[(yp + 3) * ROWF], a3);
  }
  Gy[idx] = (a0 + a1) + (a2 + a3);
}

// x pass, 864 blocks: G[y][x][c] = sum_xp g(|x-xp|) Gy[y][xp][c]
__global__ __launch_bounds__(256) void k_gauss_x(
    const float* __restrict__ Gy, float* __restrict__ G,
    const float* __restrict__ gtab) {
  __shared__ float g[96];
  if (threadIdx.x < 96) g[threadIdx.x] = gtab[threadIdx.x];
  __syncthreads();
  const int idx = blockIdx.x * 256 + threadIdx.x;
  const int y = idx / ROWF;
  const int rem = idx - y * ROWF;
  const int x = rem / STRIDE;
  const int c = rem - x * STRIDE;
  const float* base = Gy + y * ROWF + c;
  float a0 = 0.f, a1 = 0.f, a2 = 0.f, a3 = 0.f;
#pragma unroll 6
  for (int xp = 0; xp < WW; xp += 4) {
    a0 = fmaf(g[abs(x - xp)], base[xp * STRIDE], a0);
    a1 = fmaf(g[abs(x - xp - 1)], base[(xp + 1) * STRIDE], a1);
    a2 = fmaf(g[abs(x - xp - 2)], base[(xp + 2) * STRIDE], a2);
    a3 = fmaf(g[abs(x - xp - 3)], base[(xp + 3) * STRIDE], a3);
  }
  G[idx] = (a0 + a1) + (a2 + a3);
}

// ---------------------------------------------------------------------------
// MFMA bilateral + mean-field update (+ final output). G precomputed.
// block = 512 thr = 8 waves = one 4x4 pixel tile; 576 blocks.
// R21 change vs R17: the epilogue's three global loads (Qin/U/G at the
// output pixel) are HOISTED above the MFMA chunk loop — they don't depend
// on psum, so their ~200cy L2 latency hides under the main loop instead of
// serializing after the barrier.
// ---------------------------------------------------------------------------
__global__ __launch_bounds__(512) void k_bilat(
    const float* __restrict__ U, const float* __restrict__ Qin,
    const float* __restrict__ G, const _Float16* __restrict__ QT,
    float* __restrict__ Qout, _Float16* __restrict__ QTout,
    const float* __restrict__ partial, float* __restrict__ out, int last) {
  __shared__ __half sytab[64];
  __shared__ __half2 sxtab[64];
  __shared__ float psum[8][16][24];
  __shared__ float sces;

  const int tid = threadIdx.x;
  const int w = tid >> 6;
  const int l = tid & 63;
  const int g = l >> 4;
  const int q = l & 15;

  if (tid < 64) {
    const float dv = (float)(tid - 32);
    sytab[tid] = __float2half(__expf(dv * dv * (-1.f / 18.f)));
    const float dv1 = dv + 1.f;
    sxtab[tid] = __floats2half2_rn(__expf(dv * dv * (-1.f / 18.f)),
                                   __expf(dv1 * dv1 * (-1.f / 18.f)));
    if (last) {
      float v = (tid < NBLK) ? partial[tid] : 0.f;
#pragma unroll
      for (int off = 32; off >= 1; off >>= 1) v += __shfl_xor(v, off, 64);
      if (tid == 0) sces = v * (1.f / (float)NN);
    }
  }
  __syncthreads();

  const int tile = blockIdx.x;
  const int ty0 = (tile / 24) * 4;
  const int tx0 = (tile - (tile / 24) * 24) * 4;

  const int pr = q >> 2, pc = q & 3;
  const int yi = ty0 + pr, xi = tx0 + pc;
  const int ipix = yi * WW + xi;

  const float4 rown = *(const float4*)(Qin + ipix * STRIDE + 20);
  const __half2 ri_r = __float2half2_rn(rown.y);
  const __half2 ri_g = __float2half2_rn(rown.z);
  const __half2 ri_b = __float2half2_rn(rown.w);
  const __half2 mhalf = __floats2half2_rn(-0.5f, -0.5f);
  const __half hzero = __float2half(0.f);

  // ---- epilogue indices + HOISTED loads (independent of psum/MFMA) ----
  const int half_ = l >> 5;
  const int cl = l & 31;
  const bool act = cl < CC;
  const int pix = w * 2 + half_;
  const int py = ty0 + (pix >> 2), px = tx0 + (pix & 3);
  const int ip = py * WW + px;
  float Qic = 0.f, Uc = 0.f, Gc = 0.f;
  if (cl < STRIDE) Qic = Qin[ip * STRIDE + cl];
  if (act) {
    Uc = U[ip * STRIDE + cl];
    Gc = G[ip * STRIDE + cl];
  }

  const int xs = tx0 - 16;
  const int xbase0 = (xs > 0 ? xs : 0) & ~7;
  const int rid0 = (w < 4) ? w * 23 : 92 + (w - 4) * 22;
  const int nrun = (w < 4) ? 23 : 22;
  const int row2 = (16 + q > 23) ? 23 : 16 + q;

  f32x4 acc0 = {0.f, 0.f, 0.f, 0.f};
  f32x4 acc1 = {0.f, 0.f, 0.f, 0.f};

#pragma unroll
  for (int ck = 0; ck < 6; ++ck) {
    const int r = ck * 4 + g;
    const int rid = rid0 + r;
    const int wr = rid / 5;
    const int cs = rid - wr * 5;
    const int yj = ty0 - 16 + wr;
    const int xb = xbase0 + cs * 8;
    const bool ok = (r < nrun) & (yj >= 0) & (yj < HH) & (xb <= WW - 8);
    const int yc = min(max(yj, 0), HH - 1);
    const int xc = min(xb, WW - 8);
    const _Float16* base = QT + (yc * 12 + (xc >> 3)) * 192;

    H8 b1, b2, rj, gj, bj;
    b1.v = *(const f16x8*)(base + q * 8);
    b2.v = *(const f16x8*)(base + row2 * 8);
    rj.v = *(const f16x8*)(base + 21 * 8);
    gj.v = *(const f16x8*)(base + 22 * 8);
    bj.v = *(const f16x8*)(base + 23 * 8);

    const int dy = yj - yi;
    const int iy = min(max(dy + 32, 0), 63);
    const __half syv = ok ? sytab[iy] : hzero;
    const __half2 sy2 = __half2half2(syv);
    const int dx0 = xb - xi;
    const int ix0 = min(max(dx0 + 32, 0), 57);

    H8 af;
#pragma unroll
    for (int e2 = 0; e2 < 4; ++e2) {
      const __half2 sx2 = sxtab[ix0 + 2 * e2];
      const __half2 dr = __hsub2(rj.h2[e2], ri_r);
      const __half2 dg = __hsub2(gj.h2[e2], ri_g);
      const __half2 db = __hsub2(bj.h2[e2], ri_b);
      __half2 d2c = __hmul2(dr, dr);
      d2c = __hfma2(dg, dg, d2c);
      d2c = __hfma2(db, db, d2c);
      const __half2 ec = h2exp(__hmul2(d2c, mhalf));
      af.h2[e2] = __hmul2(__hmul2(sy2, sx2), ec);
    }
    acc0 = __builtin_amdgcn_mfma_f32_16x16x32_f16(af.v, b1.v, acc0, 0, 0, 0);
    acc1 = __builtin_amdgcn_mfma_f32_16x16x32_f16(af.v, b2.v, acc1, 0, 0, 0);
  }

#pragma unroll
  for (int reg = 0; reg < 4; ++reg) {
    psum[w][g * 4 + reg][q] = acc0[reg];
    if (q < 8) psum[w][g * 4 + reg][16 + q] = acc1[reg];
  }
  __syncthreads();

  // ---- epilogue: pure LDS/VALU now (loads already in registers) ----
  float tcv = 0.f;
  if (act) {
    tcv = psum[0][pix][cl] + psum[1][pix][cl] + psum[2][pix][cl] +
          psum[3][pix][cl] + psum[4][pix][cl] + psum[5][pix][cl] +
          psum[6][pix][cl] + psum[7][pix][cl];
  }
  const float contrib = act ? (tcv + Gc - 2.f * Qic) : 0.f;  // self removed
  float tot = contrib;
#pragma unroll
  for (int off = 16; off >= 1; off >>= 1) tot += __shfl_xor(tot, off, 32);
  const float lc = act ? (-Uc - 10.f * (tot - contrib)) : -1e30f;
  float mxl = lc;
#pragma unroll
  for (int off = 16; off >= 1; off >>= 1)
    mxl = fmaxf(mxl, __shfl_xor(mxl, off, 32));
  const float e = act ? __expf(lc - mxl) : 0.f;
  float se = e;
#pragma unroll
  for (int off = 16; off >= 1; off >>= 1) se += __shfl_xor(se, off, 32);
  const float qnew = e / se;
  if (last) {
    if (act) out[cl * NN + ip] = sces + qnew;    // final CHW output
  } else {
    if (cl < STRIDE) Qout[ip * STRIDE + cl] = act ? qnew : Qic;
    if (act) QTout[(ip >> 3) * 192 + cl * 8 + (ip & 7)] = (_Float16)qnew;
  }
}

extern "C" void kernel_launch(void* const* d_in, const int* in_sizes, int n_in,
                              void* d_out, int out_size, void* d_ws,
                              size_t ws_size, hipStream_t stream) {
  const float* logits = (const float*)d_in[0];
  const int* labels = (const int*)d_in[1];
  const float* image = (const float*)d_in[2];
  float* ws = (float*)d_ws;

  float* U = ws;
  float* Qa = U + NN * STRIDE;
  float* Qb = Qa + NN * STRIDE;
  float* Gy = Qb + NN * STRIDE;
  float* G = Gy + NN * STRIDE;
  float* gtab = G + NN * STRIDE;
  float* partial = gtab + 96;
  float* cepad = partial + 64;
  _Float16* QTa = (_Float16*)(cepad + 64);
  _Float16* QTb = QTa + NRUN * 192;

  k_setup<<<NBLK, 256, 0, stream>>>(logits, labels, image, U, Qa, QTa, QTb,
                                    gtab, partial);

  const float* qi = Qa;
  float* qo = Qb;
  const _Float16* qti = QTa;
  _Float16* qto = QTb;
  const int gblk = NN * STRIDE / 256;  // 864
  for (int it = 0; it < 5; ++it) {
    k_gauss_y<<<gblk, 256, 0, stream>>>(qi, Gy, gtab);
    k_gauss_x<<<gblk, 256, 0, stream>>>(Gy, G, gtab);
    k_bilat<<<NTILE, 512, 0, stream>>>(U, qi, G, qti, qo, qto, partial,
                                       (float*)d_out, it == 4);
    qi = qo;
    qo = (qo == Qb) ? Qa : Qb;
    const _Float16* tmp = qti;
    qti = qto;
    qto = (_Float16*)tmp;
  }
}